// Round 1
// baseline (10.235 us; speedup 1.0000x reference)
//
#include <hip/hip_runtime.h>

// Elementwise collapse of the diagonal interval-bound propagation.
// lower[i] = max(wl,0)*lb + min(wl,0)*ub
// upper[i] = max(wu,0)*ub + min(wu,0)*lb + cross_strict*(-su*lb)
__global__ void ReluTransformer_89446988907158_kernel(
    const float* __restrict__ lb_in,
    const float* __restrict__ ub_in,
    const float* __restrict__ alpha_in,
    float* __restrict__ out,   // [0:n] = lower, [n:2n] = upper
    int n) {
    int i = blockIdx.x * blockDim.x + threadIdx.x;
    if (i >= n) return;

    float l = lb_in[i];
    float u = ub_in[i];
    float a = alpha_in[i];
    a = fminf(fmaxf(a, 0.0f), 1.0f);          // clamp-STE forward value

    float su = u / (u - l);                   // slope_upper (denominator > 0 by construction)

    float pos     = (l >= 0.0f && u >= 0.0f) ? 1.0f : 0.0f;
    float cross   = (l <  0.0f && u >= 0.0f) ? 1.0f : 0.0f;
    float cross_s = (l <  0.0f && u >  0.0f) ? 1.0f : 0.0f;

    float wl = pos + cross * a;
    float wu = pos + cross * su;

    float lower = fmaxf(wl, 0.0f) * l + fminf(wl, 0.0f) * u;
    float upper = fmaxf(wu, 0.0f) * u + fminf(wu, 0.0f) * l
                + cross_s * (-su * l);

    out[i]     = lower;
    out[n + i] = upper;
}

extern "C" void kernel_launch(void* const* d_in, const int* in_sizes, int n_in,
                              void* d_out, int out_size, void* d_ws, size_t ws_size,
                              hipStream_t stream) {
    const float* lb    = (const float*)d_in[0];
    const float* ub    = (const float*)d_in[1];
    const float* alpha = (const float*)d_in[2];
    float* out = (float*)d_out;
    int n = in_sizes[0];   // 8192

    const int block = 256;
    const int grid  = (n + block - 1) / block;
    ReluTransformer_89446988907158_kernel<<<grid, block, 0, stream>>>(
        lb, ub, alpha, out, n);
}

// Round 2
// 9.495 us; speedup vs baseline: 1.0780x; 1.0780x over previous
//
#include <hip/hip_runtime.h>

// Elementwise collapse of the diagonal interval-bound propagation, float4-vectorized.
// lower[i] = max(wl,0)*lb + min(wl,0)*ub
// upper[i] = max(wu,0)*ub + min(wu,0)*lb + cross_strict*(-su*lb)
__device__ __forceinline__ void compute_one(float l, float u, float a,
                                            float& lower, float& upper) {
    a = fminf(fmaxf(a, 0.0f), 1.0f);          // clamp-STE forward value
    float su = u / (u - l);                   // slope_upper (denom > 0 by construction)

    float pos     = (l >= 0.0f && u >= 0.0f) ? 1.0f : 0.0f;
    float cross   = (l <  0.0f && u >= 0.0f) ? 1.0f : 0.0f;
    float cross_s = (l <  0.0f && u >  0.0f) ? 1.0f : 0.0f;

    float wl = pos + cross * a;
    float wu = pos + cross * su;

    lower = fmaxf(wl, 0.0f) * l + fminf(wl, 0.0f) * u;
    upper = fmaxf(wu, 0.0f) * u + fminf(wu, 0.0f) * l + cross_s * (-su * l);
}

__global__ void ReluTransformer_89446988907158_kernel(
    const float4* __restrict__ lb_in,
    const float4* __restrict__ ub_in,
    const float4* __restrict__ alpha_in,
    float4* __restrict__ out_lo,   // d_out[0:n]
    float4* __restrict__ out_hi,   // d_out[n:2n]
    int n4) {
    int i = blockIdx.x * blockDim.x + threadIdx.x;
    if (i >= n4) return;

    float4 l4 = lb_in[i];
    float4 u4 = ub_in[i];
    float4 a4 = alpha_in[i];
    float4 lo, hi;
    compute_one(l4.x, u4.x, a4.x, lo.x, hi.x);
    compute_one(l4.y, u4.y, a4.y, lo.y, hi.y);
    compute_one(l4.z, u4.z, a4.z, lo.z, hi.z);
    compute_one(l4.w, u4.w, a4.w, lo.w, hi.w);

    out_lo[i] = lo;
    out_hi[i] = hi;
}

extern "C" void kernel_launch(void* const* d_in, const int* in_sizes, int n_in,
                              void* d_out, int out_size, void* d_ws, size_t ws_size,
                              hipStream_t stream) {
    const float4* lb    = (const float4*)d_in[0];
    const float4* ub    = (const float4*)d_in[1];
    const float4* alpha = (const float4*)d_in[2];
    float* out = (float*)d_out;
    int n  = in_sizes[0];   // 8192 (multiple of 4)
    int n4 = n / 4;

    const int block = 256;
    const int grid  = (n4 + block - 1) / block;   // 8 blocks
    ReluTransformer_89446988907158_kernel<<<grid, block, 0, stream>>>(
        lb, ub, alpha, (float4*)out, (float4*)(out + n), n4);
}